// Round 11
// baseline (6512.350 us; speedup 1.0000x reference)
//
#include <hip/hip_runtime.h>
#include <hip/hip_fp16.h>

// ---------------- dimensions ----------------
constexpr int T_IN = 4096, W_IN = 128;
constexpr int H1 = 4092, W1 = 124, C1 = 16;
constexpr int H2 = 4088, W2 = 120, C2 = 32;
constexpr int H3 = 4084, W3 = 116, C3 = 64;
constexpr int HP = 4080, WPW = 58;      // pooled
constexpr int KF = 3712;                // 64*58 flattened features

typedef float f32x16 __attribute__((ext_vector_type(16)));

// 25 input taps as NAMED scalars
#define LOAD25(SRC, W) \
    float p00=(SRC)[0],        p01=(SRC)[1],        p02=(SRC)[2],        p03=(SRC)[3],        p04=(SRC)[4]; \
    float p10=(SRC)[(W)],      p11=(SRC)[(W)+1],    p12=(SRC)[(W)+2],    p13=(SRC)[(W)+3],    p14=(SRC)[(W)+4]; \
    float p20=(SRC)[2*(W)],    p21=(SRC)[2*(W)+1],  p22=(SRC)[2*(W)+2],  p23=(SRC)[2*(W)+3],  p24=(SRC)[2*(W)+4]; \
    float p30=(SRC)[3*(W)],    p31=(SRC)[3*(W)+1],  p32=(SRC)[3*(W)+2],  p33=(SRC)[3*(W)+3],  p34=(SRC)[3*(W)+4]; \
    float p40=(SRC)[4*(W)],    p41=(SRC)[4*(W)+1],  p42=(SRC)[4*(W)+2],  p43=(SRC)[4*(W)+3],  p44=(SRC)[4*(W)+4];

#define TAPS25(T) \
    T(p00, 0)  T(p01, 1)  T(p02, 2)  T(p03, 3)  T(p04, 4) \
    T(p10, 5)  T(p11, 6)  T(p12, 7)  T(p13, 8)  T(p14, 9) \
    T(p20,10)  T(p21,11)  T(p22,12)  T(p23,13)  T(p24,14) \
    T(p30,15)  T(p31,16)  T(p32,17)  T(p33,18)  T(p34,19) \
    T(p40,20)  T(p41,21)  T(p42,22)  T(p43,23)  T(p44,24)

// ---------------- conv1: 1 -> 16, packed weights [k*16+co] ----------------
__global__ __launch_bounds__(256, 2) void conv1_k(const float* __restrict__ x,
        const float* __restrict__ wp, const float* __restrict__ b,
        float* __restrict__ out) {
    int pos = blockIdx.x * 256 + threadIdx.x;
    if (pos >= H1 * W1) return;
    int h = pos / W1, wi = pos - h * W1;
    const float* src = x + h * W_IN + wi;
    f32x16 acc = *(const f32x16*)b;
    LOAD25(src, W_IN);
#define T1(P, K) { f32x16 wv = *(const f32x16*)(wp + (K) * 16); \
    _Pragma("unroll") for (int i = 0; i < 16; i++) acc[i] = fmaf((P), wv[i], acc[i]); }
    TAPS25(T1)
#undef T1
#pragma unroll
    for (int i = 0; i < 16; i++) out[(size_t)i * (H1 * W1) + pos] = acc[i];
}

// ---------------- conv2: 16 -> 32, weights [(ci*25+k)*32+co] --------------
__global__ __launch_bounds__(256, 2) void conv2_k(const float* __restrict__ in,
        const float* __restrict__ wp, const float* __restrict__ b,
        float* __restrict__ out) {
    int pos = blockIdx.x * 256 + threadIdx.x;
    if (pos >= H2 * W2) return;
    int h = pos / W2, wi = pos - h * W2;
    f32x16 aA = *(const f32x16*)b;
    f32x16 aB = *(const f32x16*)(b + 16);
#pragma unroll 1
    for (int ci = 0; ci < C1; ci++) {
        const float* src = in + (size_t)ci * (H1 * W1) + h * W1 + wi;
        const float* wb = wp + ci * 25 * C2;
        LOAD25(src, W1);
#define T2(P, K) { const f32x16* wv = (const f32x16*)(wb + (K) * C2); \
    f32x16 w0 = wv[0], w1 = wv[1]; \
    _Pragma("unroll") for (int i = 0; i < 16; i++) { \
        aA[i] = fmaf((P), w0[i], aA[i]); aB[i] = fmaf((P), w1[i], aB[i]); } }
        TAPS25(T2)
#undef T2
    }
#pragma unroll
    for (int i = 0; i < 16; i++) {
        out[(size_t)i * (H2 * W2) + pos] = aA[i];
        out[(size_t)(16 + i) * (H2 * W2) + pos] = aB[i];
    }
}

// ---------------- conv3: 32 -> 64, weights [(ci*25+k)*64+co], fp16 out ----
__global__ __launch_bounds__(256, 2) void conv3_k(const float* __restrict__ in,
        const float* __restrict__ wp, const float* __restrict__ b,
        __half* __restrict__ out) {
    int pos = blockIdx.x * 256 + threadIdx.x;
    if (pos >= H3 * W3) return;
    int h = pos / W3, wi = pos - h * W3;
    f32x16 aA = *(const f32x16*)b;
    f32x16 aB = *(const f32x16*)(b + 16);
    f32x16 aC = *(const f32x16*)(b + 32);
    f32x16 aD = *(const f32x16*)(b + 48);
#pragma unroll 1
    for (int ci = 0; ci < C2; ci++) {
        const float* src = in + (size_t)ci * (H2 * W2) + h * W2 + wi;
        const float* wb = wp + ci * 25 * C3;
        LOAD25(src, W2);
#define T3(P, K) { const f32x16* wv = (const f32x16*)(wb + (K) * C3); \
    f32x16 w0 = wv[0], w1 = wv[1], w2 = wv[2], w3 = wv[3]; \
    _Pragma("unroll") for (int i = 0; i < 16; i++) { \
        aA[i] = fmaf((P), w0[i], aA[i]); aB[i] = fmaf((P), w1[i], aB[i]); \
        aC[i] = fmaf((P), w2[i], aC[i]); aD[i] = fmaf((P), w3[i], aD[i]); } }
        TAPS25(T3)
#undef T3
    }
#pragma unroll
    for (int i = 0; i < 16; i++) {
        out[(size_t)i * (H3 * W3) + pos] = __float2half(aA[i]);
        out[(size_t)(16 + i) * (H3 * W3) + pos] = __float2half(aB[i]);
        out[(size_t)(32 + i) * (H3 * W3) + pos] = __float2half(aC[i]);
        out[(size_t)(48 + i) * (H3 * W3) + pos] = __float2half(aD[i]);
    }
}

// ---------------- maxpool 5x2 stride 1,2 ----------------
__global__ __launch_bounds__(256) void pool_k(const __half* __restrict__ in,
        float* __restrict__ out) {
    int idx = blockIdx.x * 256 + threadIdx.x;
    if (idx >= C3 * HP * WPW) return;
    int w = idx % WPW; int rest = idx / WPW; int h = rest % HP; int c = rest / HP;
    const __half* base = in + (size_t)c * (H3 * W3) + (size_t)h * W3 + 2 * w;
    float m = -1e30f;
#pragma unroll
    for (int i = 0; i < 5; i++)
#pragma unroll
        for (int j = 0; j < 2; j++)
            m = fmaxf(m, __half2float(base[(size_t)i * W3 + j]));
    out[idx] = m;   // layout == flat view (HP, 3712)
}

// ---------------- lin1: (4080 x 3712) @ Wt(3712 x 64), K-split + atomics ---
__global__ __launch_bounds__(256, 2) void lin1_k(const float* __restrict__ X,
        const float* __restrict__ Wt, float* __restrict__ L) {
    __shared__ alignas(16) float Xs[64][68];
    int tid = threadIdx.x;
    int j = tid & 63, mg = tid >> 6;
    int m0 = blockIdx.x * 64;
    int c0 = blockIdx.y * 15;
    int c1 = (c0 + 15 < 58) ? c0 + 15 : 58;
    float4 la0 = {0.f,0.f,0.f,0.f}, la1 = la0, la2 = la0, la3 = la0;
    for (int cc = c0; cc < c1; cc++) {
        int k0 = cc * 64;
        __syncthreads();
#pragma unroll
        for (int tix = 0; tix < 16; tix++) {
            int idx = tid + tix * 256;
            int mm = idx >> 6, kk = idx & 63;
            int m = m0 + mm;
            Xs[kk][mm] = (m < HP) ? X[(size_t)m * KF + k0 + kk] : 0.f;
        }
        __syncthreads();
#pragma unroll 4
        for (int k = 0; k < 64; k++) {
            float wv = Wt[(size_t)(k0 + k) * 64 + j];
            const float4* xr = (const float4*)&Xs[k][mg * 16];
            float4 x0 = xr[0], x1 = xr[1], x2 = xr[2], x3 = xr[3];
            la0.x = fmaf(x0.x, wv, la0.x); la0.y = fmaf(x0.y, wv, la0.y);
            la0.z = fmaf(x0.z, wv, la0.z); la0.w = fmaf(x0.w, wv, la0.w);
            la1.x = fmaf(x1.x, wv, la1.x); la1.y = fmaf(x1.y, wv, la1.y);
            la1.z = fmaf(x1.z, wv, la1.z); la1.w = fmaf(x1.w, wv, la1.w);
            la2.x = fmaf(x2.x, wv, la2.x); la2.y = fmaf(x2.y, wv, la2.y);
            la2.z = fmaf(x2.z, wv, la2.z); la2.w = fmaf(x2.w, wv, la2.w);
            la3.x = fmaf(x3.x, wv, la3.x); la3.y = fmaf(x3.y, wv, la3.y);
            la3.z = fmaf(x3.z, wv, la3.z); la3.w = fmaf(x3.w, wv, la3.w);
        }
    }
    int mb = m0 + mg * 16;
#define LATOM(C, OFF) { int m = mb + (OFF); if (m < HP) atomicAdd(&L[(size_t)m * 64 + j], (C)); }
    LATOM(la0.x, 0)  LATOM(la0.y, 1)  LATOM(la0.z, 2)  LATOM(la0.w, 3)
    LATOM(la1.x, 4)  LATOM(la1.y, 5)  LATOM(la1.z, 6)  LATOM(la1.w, 7)
    LATOM(la2.x, 8)  LATOM(la2.y, 9)  LATOM(la2.z, 10) LATOM(la2.w, 11)
    LATOM(la3.x, 12) LATOM(la3.y, 13) LATOM(la3.z, 14) LATOM(la3.w, 15)
#undef LATOM
}

// ---------------- gi = L @ wih^T + (bih + wih@l1b) ----------------
__global__ __launch_bounds__(192) void gi_k(const float* __restrict__ L,
        const float* __restrict__ wiht, const float* __restrict__ bc,
        float* __restrict__ gi) {
    __shared__ alignas(16) float Ls[64];
    int m = blockIdx.x, g = threadIdx.x;
    if (g < 64) Ls[g] = L[(size_t)m * 64 + g];
    __syncthreads();
    float acc = bc[g];
#pragma unroll
    for (int k = 0; k < 64; k++) acc = fmaf(Ls[k], wiht[k * 192 + g], acc);
    gi[(size_t)m * 192 + g] = acc;
}

// ---------------- GRU: 2 blocks x 1 wave, ZERO barriers -------------------
// Lane l computes ALL THREE gate rows of its hidden unit (192 FMAs) with
// weights in LDS (48KB, loaded once, XOR-swizzled chunks so the 64 lanes'
// row-strided ds_read_b128 spread across banks ~2-way = free). No
// __syncthreads() in the loop -> no vmcnt(0) drain -> gi prefetch and out
// stores stay off the critical path. Same-wave LDS RAW needs no barrier.
__global__ __launch_bounds__(64, 1) void gru_k(const float* __restrict__ gi0,
        const float* __restrict__ gi1, const float* __restrict__ whh,
        const float* __restrict__ bhh, float* __restrict__ e,
        float* __restrict__ t) {
    const float* gi = blockIdx.x ? gi1 : gi0;
    float* out = blockIdx.x ? t : e;
    const int l = threadIdx.x;               // hidden unit, 0..63
    __shared__ float wlds[3 * 64 * 64];      // [gate][row][chunk-swizzled] 48KB
    __shared__ alignas(64) float hs[64];
    // load lane's 3 weight rows into LDS, chunk j stored at pos j^(l&15)
#pragma unroll
    for (int G = 0; G < 3; G++) {
        const float4* src = (const float4*)(whh + (size_t)(G * 64 + l) * 64);
        float* dst = wlds + G * 4096 + l * 64;
#pragma unroll
        for (int j = 0; j < 16; j++) {
            float4 v = src[j];
            *(float4*)(dst + ((j ^ (l & 15)) << 2)) = v;
        }
    }
    float bh_r = bhh[l], bh_z = bhh[64 + l], bh_n = bhh[128 + l];
    float h = 0.f;
    hs[l] = 0.f;
    asm volatile("" ::: "memory");           // order init writes before reads
    float g0 = gi[l], g1 = gi[64 + l], g2 = gi[128 + l];
    const float4* hs4 = (const float4*)hs;
    const float* wr = wlds + l * 64;
    const float* wz = wlds + 4096 + l * 64;
    const float* wn = wlds + 8192 + l * 64;
#pragma unroll 1
    for (int m = 0; m < HP; m++) {
        float gr = g0, gz = g1, gn = g2;
        if (m + 1 < HP) {                    // prefetch next gi (no barrier to drain it)
            const float* gp = gi + (size_t)(m + 1) * 192;
            g0 = gp[l]; g1 = gp[64 + l]; g2 = gp[128 + l];
        }
        float ar0=0.f, ar1=0.f, ar2=0.f, ar3=0.f;
        float az0=0.f, az1=0.f, az2=0.f, az3=0.f;
        float an0=0.f, an1=0.f, an2=0.f, an3=0.f;
#pragma unroll
        for (int j = 0; j < 16; j++) {
            int jj = (j ^ (l & 15)) << 2;
            float4 hv = hs4[j];              // broadcast read (conflict-free)
            float4 wrv = *(const float4*)(wr + jj);
            float4 wzv = *(const float4*)(wz + jj);
            float4 wnv = *(const float4*)(wn + jj);
            ar0 = fmaf(wrv.x, hv.x, ar0); ar1 = fmaf(wrv.y, hv.y, ar1);
            ar2 = fmaf(wrv.z, hv.z, ar2); ar3 = fmaf(wrv.w, hv.w, ar3);
            az0 = fmaf(wzv.x, hv.x, az0); az1 = fmaf(wzv.y, hv.y, az1);
            az2 = fmaf(wzv.z, hv.z, az2); az3 = fmaf(wzv.w, hv.w, az3);
            an0 = fmaf(wnv.x, hv.x, an0); an1 = fmaf(wnv.y, hv.y, an1);
            an2 = fmaf(wnv.z, hv.z, an2); an3 = fmaf(wnv.w, hv.w, an3);
        }
        float ar = (ar0 + ar1) + (ar2 + ar3) + bh_r;
        float az = (az0 + az1) + (az2 + az3) + bh_z;
        float an = (an0 + an1) + (an2 + an3) + bh_n;
        float rg = 1.f / (1.f + __expf(-(gr + ar)));
        float zg = 1.f / (1.f + __expf(-(gz + az)));
        float pre = gn + rg * an;
        float ex = __expf(2.f * pre);
        float nn = 1.f - 2.f / (ex + 1.f);   // tanh, overflow-safe
        h = (1.f - zg) * nn + zg * h;
        hs[l] = h;                           // wave-ordered LDS write
        asm volatile("" ::: "memory");       // next-iter reads stay after it
        out[(size_t)m * 64 + l] = h;
    }
}

// ---------------- alignment column stats (online softmax over m) ----------
__global__ __launch_bounds__(256) void astat_k(const float* __restrict__ e,
        const float* __restrict__ t, float* __restrict__ pM,
        float* __restrict__ pZ) {
    __shared__ alignas(16) float Ts[64][68];
    __shared__ float Ms[4][64], Zs[4][64];
    int tid = threadIdx.x;
    int nl = tid & 63, ms = tid >> 6;
    int n0 = blockIdx.x * 64;
#pragma unroll
    for (int i = 0; i < 16; i++) {
        int idx = tid + i * 256;
        int rr = idx >> 6, kk = idx & 63;
        int n = n0 + rr;
        Ts[rr][kk] = (n < HP) ? t[(size_t)n * 64 + kk] : 0.f;
    }
    __syncthreads();
    float M = -1e30f, Z = 0.f;
    int m0 = blockIdx.y * 510;
    const float4* Trow = (const float4*)&Ts[nl][0];
    for (int m = m0 + ms; m < m0 + 510; m += 4) {
        const float4* er = (const float4*)(e + (size_t)m * 64);
        float a0 = 0, a1 = 0, a2 = 0, a3 = 0;
#pragma unroll
        for (int i = 0; i < 16; i++) {
            float4 evv = er[i], tv = Trow[i];
            a0 = fmaf(evv.x, tv.x, a0); a1 = fmaf(evv.y, tv.y, a1);
            a2 = fmaf(evv.z, tv.z, a2); a3 = fmaf(evv.w, tv.w, a3);
        }
        float s = (a0 + a1) + (a2 + a3);
        float nM = fmaxf(M, s);
        Z = Z * __expf(M - nM) + __expf(s - nM);
        M = nM;
    }
    Ms[ms][nl] = M; Zs[ms][nl] = Z;
    __syncthreads();
    if (ms == 0) {
#pragma unroll
        for (int i = 1; i < 4; i++) {
            float m2 = Ms[i][nl], z2 = Zs[i][nl];
            float nM = fmaxf(M, m2);
            Z = Z * __expf(M - nM) + z2 * __expf(m2 - nM);
            M = nM;
        }
        int n = n0 + nl;
        if (n < HP) { pM[(size_t)blockIdx.y * HP + n] = M; pZ[(size_t)blockIdx.y * HP + n] = Z; }
    }
}

// ---------------- attention logits ----------------
__global__ __launch_bounds__(256) void attnlog_k(const float* __restrict__ e,
        const float* __restrict__ aw, const float* __restrict__ ab,
        float* __restrict__ alog) {
    int m = blockIdx.x * 256 + threadIdx.x;
    if (m >= HP) return;
    float acc = ab[0];
    const float4* er = (const float4*)(e + (size_t)m * 64);
    const float4* ar = (const float4*)aw;
#pragma unroll
    for (int i = 0; i < 16; i++) {
        float4 evv = er[i], av = ar[i];
        acc += evv.x * av.x + evv.y * av.y + evv.z * av.z + evv.w * av.w;
    }
    alog[m] = acc;
}

// ---------------- reduce partial stats + attn softmax stats ---------------
__global__ __launch_bounds__(256) void reduce_k(const float* __restrict__ pM,
        const float* __restrict__ pZ, float* __restrict__ Mn,
        float* __restrict__ Zn, const float* __restrict__ alog,
        float* __restrict__ scal) {
    int tid = threadIdx.x;
    if (blockIdx.x < 16) {
        int n = blockIdx.x * 256 + tid;
        if (n >= HP) return;
        float M = pM[n], Z = pZ[n];
#pragma unroll
        for (int y = 1; y < 8; y++) {
            float m2 = pM[(size_t)y * HP + n], z2 = pZ[(size_t)y * HP + n];
            float nM = fmaxf(M, m2);
            Z = Z * __expf(M - nM) + z2 * __expf(m2 - nM);
            M = nM;
        }
        Mn[n] = M; Zn[n] = Z;
    } else {
        __shared__ float red[256];
        float m = -1e30f;
        for (int i = tid; i < HP; i += 256) m = fmaxf(m, alog[i]);
        red[tid] = m; __syncthreads();
        for (int s = 128; s > 0; s >>= 1) {
            if (tid < s) red[tid] = fmaxf(red[tid], red[tid + s]);
            __syncthreads();
        }
        float Ma = red[0]; __syncthreads();
        float z = 0.f;
        for (int i = tid; i < HP; i += 256) z += __expf(alog[i] - Ma);
        red[tid] = z; __syncthreads();
        for (int s = 128; s > 0; s >>= 1) {
            if (tid < s) red[tid] += red[tid + s];
            __syncthreads();
        }
        if (tid == 0) { scal[0] = Ma; scal[1] = red[0]; }
    }
}

// ---------------- Wmat rows m<64 ----------------
__global__ __launch_bounds__(256) void wmat_k(const float* __restrict__ e,
        const float* __restrict__ t, const float* __restrict__ Mn,
        const float* __restrict__ Zn, float* __restrict__ Wm) {
    __shared__ alignas(16) float Es[64][68];
    int tid = threadIdx.x;
#pragma unroll
    for (int i = 0; i < 16; i++) {
        int idx = tid + i * 256;
        int rr = idx >> 6, kk = idx & 63;
        Es[rr][kk] = e[(size_t)rr * 64 + kk];
    }
    __syncthreads();
    int n = blockIdx.x * 256 + tid;
    if (n >= HP) return;
    float tn[64];
    const float4* tr = (const float4*)(t + (size_t)n * 64);
    float4* tn4 = (float4*)tn;
#pragma unroll
    for (int i = 0; i < 16; i++) tn4[i] = tr[i];
    float mM = Mn[n], iZ = 1.f / Zn[n];
#pragma unroll 1
    for (int m = 0; m < 64; m++) {
        const float4* Er = (const float4*)&Es[m][0];
        float a0 = 0, a1 = 0, a2 = 0, a3 = 0;
#pragma unroll
        for (int i = 0; i < 16; i++) {
            float4 evv = Er[i], tv = tn4[i];
            a0 = fmaf(evv.x, tv.x, a0); a1 = fmaf(evv.y, tv.y, a1);
            a2 = fmaf(evv.z, tv.z, a2); a3 = fmaf(evv.w, tv.w, a3);
        }
        float s = (a0 + a1) + (a2 + a3);
        Wm[(size_t)m * HP + n] = __expf(s - mM) * iZ;
    }
}

// ---------------- t_prim = Wm(64 x 4080) @ t(4080 x 64), K-split atomics ---
__global__ __launch_bounds__(256) void tprim_k(const float* __restrict__ Wm,
        const float* __restrict__ t, float* __restrict__ tp) {
    __shared__ float Ws[64][64];
    __shared__ float Ts[64][64];
    int tid = threadIdx.x;
    int n0 = blockIdx.x * 64;
#pragma unroll
    for (int i = 0; i < 16; i++) {
        int idx = tid + i * 256;
        int r = idx >> 6, c = idx & 63;
        Ws[r][c] = (n0 + c < HP) ? Wm[(size_t)r * HP + n0 + c] : 0.f;
        Ts[r][c] = (n0 + r < HP) ? t[(size_t)(n0 + r) * 64 + c] : 0.f;
    }
    __syncthreads();
    int d = tid & 63, mg = tid >> 6;
    float acc[16];
#pragma unroll
    for (int i = 0; i < 16; i++) acc[i] = 0.f;
    for (int k = 0; k < 64; k++) {
        float tv = Ts[k][d];
#pragma unroll
        for (int mm = 0; mm < 16; mm++) acc[mm] = fmaf(Ws[mg * 16 + mm][k], tv, acc[mm]);
    }
#pragma unroll
    for (int mm = 0; mm < 16; mm++)
        atomicAdd(&tp[(size_t)(mg * 16 + mm) * 64 + d], acc[mm]);
}

// ---------------- epilogue ----------------
__global__ __launch_bounds__(256) void final_k(const float* __restrict__ tp,
        const float* __restrict__ e, const float* __restrict__ alog,
        const float* __restrict__ scal, const float* __restrict__ l3w,
        const float* __restrict__ l3b, const float* __restrict__ cw,
        const float* __restrict__ cb, float* __restrict__ out) {
    __shared__ float r1[64], hid[128];
    int tid = threadIdx.x;
    float Ma = scal[0], iZa = 1.f / scal[1];
    if (tid < 64) {
        float acc = 0.f;
        for (int m = 0; m < 64; m++) {
            float a = __expf(alog[m] - Ma) * iZa;
            acc += fabsf(tp[m * 64 + tid] - e[m * 64 + tid]) * a;
        }
        r1[tid] = fmaxf(acc, 0.f);
    }
    __syncthreads();
    if (tid < 128) {
        float acc = l3b[tid];
        for (int d = 0; d < 64; d++) acc = fmaf(r1[d], l3w[tid * 64 + d], acc);
        hid[tid] = fmaxf(acc, 0.f);
    }
    __syncthreads();
    if (tid < 2) {
        float acc = cb[tid];
        for (int j = 0; j < 128; j++) acc = fmaf(hid[j], cw[tid * 128 + j], acc);
        out[tid] = acc;
    }
}

// ---------------- weight packing ----------------
__global__ __launch_bounds__(256) void transpose_l1w_k(const float* __restrict__ w,
        float* __restrict__ wt) {
    int idx = blockIdx.x * 256 + threadIdx.x;
    if (idx >= KF * 64) return;
    int k = idx >> 6, j = idx & 63;
    wt[idx] = w[(size_t)j * KF + k];
}
__global__ __launch_bounds__(256) void pack_w1_k(const float* __restrict__ w,
        float* __restrict__ wp) {
    int idx = blockIdx.x * 256 + threadIdx.x;
    if (idx >= 400) return;
    int k = idx >> 4, co = idx & 15;
    wp[idx] = w[co * 25 + k];
}
__global__ __launch_bounds__(256) void pack_w2_k(const float* __restrict__ w,
        float* __restrict__ wp) {
    int idx = blockIdx.x * 256 + threadIdx.x;
    if (idx >= 12800) return;
    int co = idx & 31, rest = idx >> 5;
    wp[idx] = w[co * 400 + rest];
}
__global__ __launch_bounds__(256) void pack_w3_k(const float* __restrict__ w,
        float* __restrict__ wp) {
    int idx = blockIdx.x * 256 + threadIdx.x;
    if (idx >= 51200) return;
    int co = idx & 63, rest = idx >> 6;
    wp[idx] = w[co * 800 + rest];
}
__global__ __launch_bounds__(256) void pack_wih_k(const float* __restrict__ wih,
        const float* __restrict__ bih, const float* __restrict__ l1b,
        float* __restrict__ wiht, float* __restrict__ bc) {
    int idx = blockIdx.x * 256 + threadIdx.x;
    if (idx < 12288) {
        int g = idx % 192, k = idx / 192;
        wiht[idx] = wih[g * 64 + k];
    }
    if (idx < 192) {
        float acc = bih[idx];
#pragma unroll
        for (int k = 0; k < 64; k++) acc = fmaf(wih[idx * 64 + k], l1b[k], acc);
        bc[idx] = acc;
    }
}

// ---------------- host ----------------
extern "C" void kernel_launch(void* const* d_in, const int* in_sizes, int n_in,
                              void* d_out, int out_size, void* d_ws, size_t ws_size,
                              hipStream_t stream) {
    const float* ev    = (const float*)d_in[0];
    const float* tmpl  = (const float*)d_in[1];
    const float* w1    = (const float*)d_in[2];
    const float* b1    = (const float*)d_in[3];
    const float* w2    = (const float*)d_in[4];
    const float* b2    = (const float*)d_in[5];
    const float* w3    = (const float*)d_in[6];
    const float* b3    = (const float*)d_in[7];
    const float* l1w   = (const float*)d_in[8];
    const float* l1b   = (const float*)d_in[9];
    const float* wih   = (const float*)d_in[10];
    const float* whh   = (const float*)d_in[11];
    const float* bih   = (const float*)d_in[12];
    const float* bhh   = (const float*)d_in[13];
    const float* aw    = (const float*)d_in[14];
    const float* ab    = (const float*)d_in[15];
    const float* l3w   = (const float*)d_in[16];
    const float* l3b   = (const float*)d_in[17];
    const float* cw    = (const float*)d_in[18];
    const float* cb    = (const float*)d_in[19];
    float* out = (float*)d_out;
    (void)in_sizes; (void)n_in; (void)out_size;

    char* ws = (char*)d_ws;
    size_t off = 0;
    auto alloc = [&](size_t bytes) -> char* {
        char* p = ws + off;
        off += (bytes + 255) & ~(size_t)255;
        return p;
    };
    size_t szA = (size_t)C3 * H3 * W3 * 2;                 // fp16 conv3 out
    size_t szA1 = (size_t)C1 * H1 * W1 * 4;                // fp32 conv1 out
    if (szA1 > szA) szA = szA1;
    char*  A    = alloc(szA);
    float* B    = (float*)alloc((size_t)C2 * H2 * W2 * 4); // conv2 out / pooled
    float* Wt   = (float*)alloc((size_t)KF * 64 * 4);
    float* w1p  = (float*)alloc(400 * 4);
    float* w2p  = (float*)alloc(12800 * 4);
    float* w3p  = (float*)alloc(51200 * 4);
    float* wiht = (float*)alloc(12288 * 4);
    float* bc   = (float*)alloc(256 * 4);
    float* L    = (float*)alloc((size_t)HP * 64 * 4);
    float* gi0  = (float*)alloc((size_t)HP * 192 * 4);
    float* gi1  = (float*)alloc((size_t)HP * 192 * 4);
    float* ebuf = (float*)alloc((size_t)HP * 64 * 4);
    float* tbuf = (float*)alloc((size_t)HP * 64 * 4);
    float* pM   = (float*)alloc((size_t)8 * HP * 4);
    float* pZ   = (float*)alloc((size_t)8 * HP * 4);
    float* Mn   = (float*)alloc(HP * 4);
    float* Zn   = (float*)alloc(HP * 4);
    float* Wm   = (float*)alloc((size_t)64 * HP * 4);
    float* alog = (float*)alloc(HP * 4);
    float* tpm  = (float*)alloc(64 * 64 * 4);
    float* scal = (float*)alloc(256);
    if (off > ws_size) return;   // workspace too small: bail loudly (validation fails)

    transpose_l1w_k<<<dim3((KF * 64 + 255) / 256), dim3(256), 0, stream>>>(l1w, Wt);
    pack_w1_k<<<dim3(2), dim3(256), 0, stream>>>(w1, w1p);
    pack_w2_k<<<dim3(50), dim3(256), 0, stream>>>(w2, w2p);
    pack_w3_k<<<dim3(200), dim3(256), 0, stream>>>(w3, w3p);
    pack_wih_k<<<dim3(48), dim3(256), 0, stream>>>(wih, bih, l1b, wiht, bc);

    for (int bsel = 0; bsel < 2; bsel++) {
        const float* xin = bsel ? tmpl : ev;
        float* gib = bsel ? gi1 : gi0;
        conv1_k<<<dim3((H1 * W1 + 255) / 256), dim3(256), 0, stream>>>(xin, w1p, b1, (float*)A);
        conv2_k<<<dim3((H2 * W2 + 255) / 256), dim3(256), 0, stream>>>((const float*)A, w2p, b2, B);
        conv3_k<<<dim3((H3 * W3 + 255) / 256), dim3(256), 0, stream>>>(B, w3p, b3, (__half*)A);
        pool_k<<<dim3((C3 * HP * WPW + 255) / 256), dim3(256), 0, stream>>>((const __half*)A, B);
        hipMemsetAsync(L, 0, (size_t)HP * 64 * 4, stream);
        lin1_k<<<dim3(64, 4), dim3(256), 0, stream>>>(B, Wt, L);
        gi_k<<<dim3(HP), dim3(192), 0, stream>>>(L, wiht, bc, gib);
    }
    gru_k<<<dim3(2), dim3(64), 0, stream>>>(gi0, gi1, whh, bhh, ebuf, tbuf);
    astat_k<<<dim3(64, 8), dim3(256), 0, stream>>>(ebuf, tbuf, pM, pZ);
    attnlog_k<<<dim3(16), dim3(256), 0, stream>>>(ebuf, aw, ab, alog);
    reduce_k<<<dim3(17), dim3(256), 0, stream>>>(pM, pZ, Mn, Zn, alog, scal);
    wmat_k<<<dim3(16), dim3(256), 0, stream>>>(ebuf, tbuf, Mn, Zn, Wm);
    hipMemsetAsync(tpm, 0, 64 * 64 * 4, stream);
    tprim_k<<<dim3(64), dim3(256), 0, stream>>>(Wm, tbuf, tpm);
    final_k<<<dim3(1), dim3(256), 0, stream>>>(tpm, ebuf, alog, scal, l3w, l3b, cw, cb, out);
}

// Round 14
// 4260.945 us; speedup vs baseline: 1.5284x; 1.5284x over previous
//
#include <hip/hip_runtime.h>
#include <hip/hip_fp16.h>

// ---------------- dimensions ----------------
constexpr int T_IN = 4096, W_IN = 128;
constexpr int H1 = 4092, W1 = 124, C1 = 16;
constexpr int H2 = 4088, W2 = 120, C2 = 32;
constexpr int H3 = 4084, W3 = 116, C3 = 64;
constexpr int HP = 4080, WPW = 58;      // pooled
constexpr int KF = 3712;                // 64*58 flattened features

typedef float f32x16 __attribute__((ext_vector_type(16)));

// 25 input taps as NAMED scalars
#define LOAD25(SRC, W) \
    float p00=(SRC)[0],        p01=(SRC)[1],        p02=(SRC)[2],        p03=(SRC)[3],        p04=(SRC)[4]; \
    float p10=(SRC)[(W)],      p11=(SRC)[(W)+1],    p12=(SRC)[(W)+2],    p13=(SRC)[(W)+3],    p14=(SRC)[(W)+4]; \
    float p20=(SRC)[2*(W)],    p21=(SRC)[2*(W)+1],  p22=(SRC)[2*(W)+2],  p23=(SRC)[2*(W)+3],  p24=(SRC)[2*(W)+4]; \
    float p30=(SRC)[3*(W)],    p31=(SRC)[3*(W)+1],  p32=(SRC)[3*(W)+2],  p33=(SRC)[3*(W)+3],  p34=(SRC)[3*(W)+4]; \
    float p40=(SRC)[4*(W)],    p41=(SRC)[4*(W)+1],  p42=(SRC)[4*(W)+2],  p43=(SRC)[4*(W)+3],  p44=(SRC)[4*(W)+4];

#define TAPS25(T) \
    T(p00, 0)  T(p01, 1)  T(p02, 2)  T(p03, 3)  T(p04, 4) \
    T(p10, 5)  T(p11, 6)  T(p12, 7)  T(p13, 8)  T(p14, 9) \
    T(p20,10)  T(p21,11)  T(p22,12)  T(p23,13)  T(p24,14) \
    T(p30,15)  T(p31,16)  T(p32,17)  T(p33,18)  T(p34,19) \
    T(p40,20)  T(p41,21)  T(p42,22)  T(p43,23)  T(p44,24)

// ---------------- conv1: 1 -> 16, packed weights [k*16+co] ----------------
__global__ __launch_bounds__(256, 2) void conv1_k(const float* __restrict__ x,
        const float* __restrict__ wp, const float* __restrict__ b,
        float* __restrict__ out) {
    int pos = blockIdx.x * 256 + threadIdx.x;
    if (pos >= H1 * W1) return;
    int h = pos / W1, wi = pos - h * W1;
    const float* src = x + h * W_IN + wi;
    f32x16 acc = *(const f32x16*)b;
    LOAD25(src, W_IN);
#define T1(P, K) { f32x16 wv = *(const f32x16*)(wp + (K) * 16); \
    _Pragma("unroll") for (int i = 0; i < 16; i++) acc[i] = fmaf((P), wv[i], acc[i]); }
    TAPS25(T1)
#undef T1
#pragma unroll
    for (int i = 0; i < 16; i++) out[(size_t)i * (H1 * W1) + pos] = acc[i];
}

// ---------------- conv2: 16 -> 32, weights [(ci*25+k)*32+co] --------------
__global__ __launch_bounds__(256, 2) void conv2_k(const float* __restrict__ in,
        const float* __restrict__ wp, const float* __restrict__ b,
        float* __restrict__ out) {
    int pos = blockIdx.x * 256 + threadIdx.x;
    if (pos >= H2 * W2) return;
    int h = pos / W2, wi = pos - h * W2;
    f32x16 aA = *(const f32x16*)b;
    f32x16 aB = *(const f32x16*)(b + 16);
#pragma unroll 1
    for (int ci = 0; ci < C1; ci++) {
        const float* src = in + (size_t)ci * (H1 * W1) + h * W1 + wi;
        const float* wb = wp + ci * 25 * C2;
        LOAD25(src, W1);
#define T2(P, K) { const f32x16* wv = (const f32x16*)(wb + (K) * C2); \
    f32x16 w0 = wv[0], w1 = wv[1]; \
    _Pragma("unroll") for (int i = 0; i < 16; i++) { \
        aA[i] = fmaf((P), w0[i], aA[i]); aB[i] = fmaf((P), w1[i], aB[i]); } }
        TAPS25(T2)
#undef T2
    }
#pragma unroll
    for (int i = 0; i < 16; i++) {
        out[(size_t)i * (H2 * W2) + pos] = aA[i];
        out[(size_t)(16 + i) * (H2 * W2) + pos] = aB[i];
    }
}

// ---------------- conv3: 32 -> 64, weights [(ci*25+k)*64+co], fp16 out ----
__global__ __launch_bounds__(256, 2) void conv3_k(const float* __restrict__ in,
        const float* __restrict__ wp, const float* __restrict__ b,
        __half* __restrict__ out) {
    int pos = blockIdx.x * 256 + threadIdx.x;
    if (pos >= H3 * W3) return;
    int h = pos / W3, wi = pos - h * W3;
    f32x16 aA = *(const f32x16*)b;
    f32x16 aB = *(const f32x16*)(b + 16);
    f32x16 aC = *(const f32x16*)(b + 32);
    f32x16 aD = *(const f32x16*)(b + 48);
#pragma unroll 1
    for (int ci = 0; ci < C2; ci++) {
        const float* src = in + (size_t)ci * (H2 * W2) + h * W2 + wi;
        const float* wb = wp + ci * 25 * C3;
        LOAD25(src, W2);
#define T3(P, K) { const f32x16* wv = (const f32x16*)(wb + (K) * C3); \
    f32x16 w0 = wv[0], w1 = wv[1], w2 = wv[2], w3 = wv[3]; \
    _Pragma("unroll") for (int i = 0; i < 16; i++) { \
        aA[i] = fmaf((P), w0[i], aA[i]); aB[i] = fmaf((P), w1[i], aB[i]); \
        aC[i] = fmaf((P), w2[i], aC[i]); aD[i] = fmaf((P), w3[i], aD[i]); } }
        TAPS25(T3)
#undef T3
    }
#pragma unroll
    for (int i = 0; i < 16; i++) {
        out[(size_t)i * (H3 * W3) + pos] = __float2half(aA[i]);
        out[(size_t)(16 + i) * (H3 * W3) + pos] = __float2half(aB[i]);
        out[(size_t)(32 + i) * (H3 * W3) + pos] = __float2half(aC[i]);
        out[(size_t)(48 + i) * (H3 * W3) + pos] = __float2half(aD[i]);
    }
}

// ---------------- maxpool 5x2 stride 1,2 ----------------
__global__ __launch_bounds__(256) void pool_k(const __half* __restrict__ in,
        float* __restrict__ out) {
    int idx = blockIdx.x * 256 + threadIdx.x;
    if (idx >= C3 * HP * WPW) return;
    int w = idx % WPW; int rest = idx / WPW; int h = rest % HP; int c = rest / HP;
    const __half* base = in + (size_t)c * (H3 * W3) + (size_t)h * W3 + 2 * w;
    float m = -1e30f;
#pragma unroll
    for (int i = 0; i < 5; i++)
#pragma unroll
        for (int j = 0; j < 2; j++)
            m = fmaxf(m, __half2float(base[(size_t)i * W3 + j]));
    out[idx] = m;   // layout == flat view (HP, 3712)
}

// ---------------- lin1: (4080 x 3712) @ Wt(3712 x 64), K-split + atomics ---
__global__ __launch_bounds__(256, 2) void lin1_k(const float* __restrict__ X,
        const float* __restrict__ Wt, float* __restrict__ L) {
    __shared__ alignas(16) float Xs[64][68];
    int tid = threadIdx.x;
    int j = tid & 63, mg = tid >> 6;
    int m0 = blockIdx.x * 64;
    int c0 = blockIdx.y * 15;
    int c1 = (c0 + 15 < 58) ? c0 + 15 : 58;
    float4 la0 = {0.f,0.f,0.f,0.f}, la1 = la0, la2 = la0, la3 = la0;
    for (int cc = c0; cc < c1; cc++) {
        int k0 = cc * 64;
        __syncthreads();
#pragma unroll
        for (int tix = 0; tix < 16; tix++) {
            int idx = tid + tix * 256;
            int mm = idx >> 6, kk = idx & 63;
            int m = m0 + mm;
            Xs[kk][mm] = (m < HP) ? X[(size_t)m * KF + k0 + kk] : 0.f;
        }
        __syncthreads();
#pragma unroll 4
        for (int k = 0; k < 64; k++) {
            float wv = Wt[(size_t)(k0 + k) * 64 + j];
            const float4* xr = (const float4*)&Xs[k][mg * 16];
            float4 x0 = xr[0], x1 = xr[1], x2 = xr[2], x3 = xr[3];
            la0.x = fmaf(x0.x, wv, la0.x); la0.y = fmaf(x0.y, wv, la0.y);
            la0.z = fmaf(x0.z, wv, la0.z); la0.w = fmaf(x0.w, wv, la0.w);
            la1.x = fmaf(x1.x, wv, la1.x); la1.y = fmaf(x1.y, wv, la1.y);
            la1.z = fmaf(x1.z, wv, la1.z); la1.w = fmaf(x1.w, wv, la1.w);
            la2.x = fmaf(x2.x, wv, la2.x); la2.y = fmaf(x2.y, wv, la2.y);
            la2.z = fmaf(x2.z, wv, la2.z); la2.w = fmaf(x2.w, wv, la2.w);
            la3.x = fmaf(x3.x, wv, la3.x); la3.y = fmaf(x3.y, wv, la3.y);
            la3.z = fmaf(x3.z, wv, la3.z); la3.w = fmaf(x3.w, wv, la3.w);
        }
    }
    int mb = m0 + mg * 16;
#define LATOM(C, OFF) { int m = mb + (OFF); if (m < HP) atomicAdd(&L[(size_t)m * 64 + j], (C)); }
    LATOM(la0.x, 0)  LATOM(la0.y, 1)  LATOM(la0.z, 2)  LATOM(la0.w, 3)
    LATOM(la1.x, 4)  LATOM(la1.y, 5)  LATOM(la1.z, 6)  LATOM(la1.w, 7)
    LATOM(la2.x, 8)  LATOM(la2.y, 9)  LATOM(la2.z, 10) LATOM(la2.w, 11)
    LATOM(la3.x, 12) LATOM(la3.y, 13) LATOM(la3.z, 14) LATOM(la3.w, 15)
#undef LATOM
}

// ---------------- gi = L @ wih^T + (bih + wih@l1b) ----------------
__global__ __launch_bounds__(192) void gi_k(const float* __restrict__ L,
        const float* __restrict__ wiht, const float* __restrict__ bc,
        float* __restrict__ gi) {
    __shared__ alignas(16) float Ls[64];
    int m = blockIdx.x, g = threadIdx.x;
    if (g < 64) Ls[g] = L[(size_t)m * 64 + g];
    __syncthreads();
    float acc = bc[g];
#pragma unroll
    for (int k = 0; k < 64; k++) acc = fmaf(Ls[k], wiht[k * 192 + g], acc);
    gi[(size_t)m * 192 + g] = acc;
}

// ---------------- GRU: 2 blocks x 3 waves, raw barriers (no vmcnt drain) --
// Round-7 structure (reg weights, 2 barriers) but the barriers are
// s_waitcnt lgkmcnt(0) + s_barrier ONLY. __syncthreads() would emit
// s_waitcnt vmcnt(0) which drains the gi prefetch loads and the out store
// every step (2x). LDS visibility across waves needs only lgkm.
__global__ __launch_bounds__(192, 1) void gru_k(const float* __restrict__ gi0,
        const float* __restrict__ gi1, const float* __restrict__ whh,
        const float* __restrict__ bhh, float* __restrict__ e,
        float* __restrict__ t) {
    const float* gi = blockIdx.x ? gi1 : gi0;
    float* out = blockIdx.x ? t : e;
    const int g = threadIdx.x;           // gate row, 0..191
    const f32x16* wp = (const f32x16*)(whh + (size_t)g * 64);
    f32x16 w0 = wp[0], w1 = wp[1], w2 = wp[2], w3 = wp[3];
    float bh = bhh[g];
    __shared__ alignas(64) float hs[64];
    __shared__ float Ax[192];
    const f32x16* hsv = (const f32x16*)hs;
    float h = 0.f;
    if (g < 64) hs[g] = 0.f;
    __syncthreads();
    float p0 = 0.f, p1 = 0.f, p2 = 0.f;  // gi prefetch (lanes<64 only)
    if (g < 64) { p0 = gi[g]; p1 = gi[64 + g]; p2 = gi[128 + g]; }
#define LGKM_BARRIER() do { \
    asm volatile("s_waitcnt lgkmcnt(0)" ::: "memory"); \
    __builtin_amdgcn_s_barrier(); \
    asm volatile("" ::: "memory"); \
} while (0)
#pragma unroll 1
    for (int m = 0; m < HP; m++) {
        f32x16 hv0 = hsv[0], hv1 = hsv[1], hv2 = hsv[2], hv3 = hsv[3];
        float c0 = p0, c1 = p1, c2 = p2;
        if (g < 64 && m + 1 < HP) {
            const float* gp = gi + (size_t)(m + 1) * 192;
            p0 = gp[g]; p1 = gp[64 + g]; p2 = gp[128 + g];
        }
        float a0 = 0.f, a1 = 0.f, a2 = 0.f, a3 = 0.f;
#pragma unroll
        for (int i = 0; i < 16; i++) {
            a0 = fmaf(w0[i], hv0[i], a0);
            a1 = fmaf(w1[i], hv1[i], a1);
            a2 = fmaf(w2[i], hv2[i], a2);
            a3 = fmaf(w3[i], hv3[i], a3);
        }
        float a = (a0 + a1) + (a2 + a3) + bh;
        Ax[g] = a;
        LGKM_BARRIER();                       // Ax visible; no vmcnt drain
        if (g < 64) {
            float az = Ax[64 + g], an = Ax[128 + g];
            float rg = 1.f / (1.f + __expf(-(c0 + a)));
            float zg = 1.f / (1.f + __expf(-(c1 + az)));
            float pre = c2 + rg * an;
            float ex = __expf(2.f * pre);
            float nn = 1.f - 2.f / (ex + 1.f);      // tanh, overflow-safe
            h = (1.f - zg) * nn + zg * h;
            hs[g] = h;
            out[(size_t)m * 64 + g] = h;            // store stays in flight
        }
        LGKM_BARRIER();                       // h visible; no vmcnt drain
    }
#undef LGKM_BARRIER
}

// ---------------- alignment column stats (online softmax over m) ----------
__global__ __launch_bounds__(256) void astat_k(const float* __restrict__ e,
        const float* __restrict__ t, float* __restrict__ pM,
        float* __restrict__ pZ) {
    __shared__ alignas(16) float Ts[64][68];
    __shared__ float Ms[4][64], Zs[4][64];
    int tid = threadIdx.x;
    int nl = tid & 63, ms = tid >> 6;
    int n0 = blockIdx.x * 64;
#pragma unroll
    for (int i = 0; i < 16; i++) {
        int idx = tid + i * 256;
        int rr = idx >> 6, kk = idx & 63;
        int n = n0 + rr;
        Ts[rr][kk] = (n < HP) ? t[(size_t)n * 64 + kk] : 0.f;
    }
    __syncthreads();
    float M = -1e30f, Z = 0.f;
    int m0 = blockIdx.y * 510;
    const float4* Trow = (const float4*)&Ts[nl][0];
    for (int m = m0 + ms; m < m0 + 510; m += 4) {
        const float4* er = (const float4*)(e + (size_t)m * 64);
        float a0 = 0, a1 = 0, a2 = 0, a3 = 0;
#pragma unroll
        for (int i = 0; i < 16; i++) {
            float4 evv = er[i], tv = Trow[i];
            a0 = fmaf(evv.x, tv.x, a0); a1 = fmaf(evv.y, tv.y, a1);
            a2 = fmaf(evv.z, tv.z, a2); a3 = fmaf(evv.w, tv.w, a3);
        }
        float s = (a0 + a1) + (a2 + a3);
        float nM = fmaxf(M, s);
        Z = Z * __expf(M - nM) + __expf(s - nM);
        M = nM;
    }
    Ms[ms][nl] = M; Zs[ms][nl] = Z;
    __syncthreads();
    if (ms == 0) {
#pragma unroll
        for (int i = 1; i < 4; i++) {
            float m2 = Ms[i][nl], z2 = Zs[i][nl];
            float nM = fmaxf(M, m2);
            Z = Z * __expf(M - nM) + z2 * __expf(m2 - nM);
            M = nM;
        }
        int n = n0 + nl;
        if (n < HP) { pM[(size_t)blockIdx.y * HP + n] = M; pZ[(size_t)blockIdx.y * HP + n] = Z; }
    }
}

// ---------------- attention logits ----------------
__global__ __launch_bounds__(256) void attnlog_k(const float* __restrict__ e,
        const float* __restrict__ aw, const float* __restrict__ ab,
        float* __restrict__ alog) {
    int m = blockIdx.x * 256 + threadIdx.x;
    if (m >= HP) return;
    float acc = ab[0];
    const float4* er = (const float4*)(e + (size_t)m * 64);
    const float4* ar = (const float4*)aw;
#pragma unroll
    for (int i = 0; i < 16; i++) {
        float4 evv = er[i], av = ar[i];
        acc += evv.x * av.x + evv.y * av.y + evv.z * av.z + evv.w * av.w;
    }
    alog[m] = acc;
}

// ---------------- reduce partial stats + attn softmax stats ---------------
__global__ __launch_bounds__(256) void reduce_k(const float* __restrict__ pM,
        const float* __restrict__ pZ, float* __restrict__ Mn,
        float* __restrict__ Zn, const float* __restrict__ alog,
        float* __restrict__ scal) {
    int tid = threadIdx.x;
    if (blockIdx.x < 16) {
        int n = blockIdx.x * 256 + tid;
        if (n >= HP) return;
        float M = pM[n], Z = pZ[n];
#pragma unroll
        for (int y = 1; y < 8; y++) {
            float m2 = pM[(size_t)y * HP + n], z2 = pZ[(size_t)y * HP + n];
            float nM = fmaxf(M, m2);
            Z = Z * __expf(M - nM) + z2 * __expf(m2 - nM);
            M = nM;
        }
        Mn[n] = M; Zn[n] = Z;
    } else {
        __shared__ float red[256];
        float m = -1e30f;
        for (int i = tid; i < HP; i += 256) m = fmaxf(m, alog[i]);
        red[tid] = m; __syncthreads();
        for (int s = 128; s > 0; s >>= 1) {
            if (tid < s) red[tid] = fmaxf(red[tid], red[tid + s]);
            __syncthreads();
        }
        float Ma = red[0]; __syncthreads();
        float z = 0.f;
        for (int i = tid; i < HP; i += 256) z += __expf(alog[i] - Ma);
        red[tid] = z; __syncthreads();
        for (int s = 128; s > 0; s >>= 1) {
            if (tid < s) red[tid] += red[tid + s];
            __syncthreads();
        }
        if (tid == 0) { scal[0] = Ma; scal[1] = red[0]; }
    }
}

// ---------------- Wmat rows m<64 ----------------
__global__ __launch_bounds__(256) void wmat_k(const float* __restrict__ e,
        const float* __restrict__ t, const float* __restrict__ Mn,
        const float* __restrict__ Zn, float* __restrict__ Wm) {
    __shared__ alignas(16) float Es[64][68];
    int tid = threadIdx.x;
#pragma unroll
    for (int i = 0; i < 16; i++) {
        int idx = tid + i * 256;
        int rr = idx >> 6, kk = idx & 63;
        Es[rr][kk] = e[(size_t)rr * 64 + kk];
    }
    __syncthreads();
    int n = blockIdx.x * 256 + tid;
    if (n >= HP) return;
    float tn[64];
    const float4* tr = (const float4*)(t + (size_t)n * 64);
    float4* tn4 = (float4*)tn;
#pragma unroll
    for (int i = 0; i < 16; i++) tn4[i] = tr[i];
    float mM = Mn[n], iZ = 1.f / Zn[n];
#pragma unroll 1
    for (int m = 0; m < 64; m++) {
        const float4* Er = (const float4*)&Es[m][0];
        float a0 = 0, a1 = 0, a2 = 0, a3 = 0;
#pragma unroll
        for (int i = 0; i < 16; i++) {
            float4 evv = Er[i], tv = tn4[i];
            a0 = fmaf(evv.x, tv.x, a0); a1 = fmaf(evv.y, tv.y, a1);
            a2 = fmaf(evv.z, tv.z, a2); a3 = fmaf(evv.w, tv.w, a3);
        }
        float s = (a0 + a1) + (a2 + a3);
        Wm[(size_t)m * HP + n] = __expf(s - mM) * iZ;
    }
}

// ---------------- t_prim = Wm(64 x 4080) @ t(4080 x 64), K-split atomics ---
__global__ __launch_bounds__(256) void tprim_k(const float* __restrict__ Wm,
        const float* __restrict__ t, float* __restrict__ tp) {
    __shared__ float Ws[64][64];
    __shared__ float Ts[64][64];
    int tid = threadIdx.x;
    int n0 = blockIdx.x * 64;
#pragma unroll
    for (int i = 0; i < 16; i++) {
        int idx = tid + i * 256;
        int r = idx >> 6, c = idx & 63;
        Ws[r][c] = (n0 + c < HP) ? Wm[(size_t)r * HP + n0 + c] : 0.f;
        Ts[r][c] = (n0 + r < HP) ? t[(size_t)(n0 + r) * 64 + c] : 0.f;
    }
    __syncthreads();
    int d = tid & 63, mg = tid >> 6;
    float acc[16];
#pragma unroll
    for (int i = 0; i < 16; i++) acc[i] = 0.f;
    for (int k = 0; k < 64; k++) {
        float tv = Ts[k][d];
#pragma unroll
        for (int mm = 0; mm < 16; mm++) acc[mm] = fmaf(Ws[mg * 16 + mm][k], tv, acc[mm]);
    }
#pragma unroll
    for (int mm = 0; mm < 16; mm++)
        atomicAdd(&tp[(size_t)(mg * 16 + mm) * 64 + d], acc[mm]);
}

// ---------------- epilogue ----------------
__global__ __launch_bounds__(256) void final_k(const float* __restrict__ tp,
        const float* __restrict__ e, const float* __restrict__ alog,
        const float* __restrict__ scal, const float* __restrict__ l3w,
        const float* __restrict__ l3b, const float* __restrict__ cw,
        const float* __restrict__ cb, float* __restrict__ out) {
    __shared__ float r1[64], hid[128];
    int tid = threadIdx.x;
    float Ma = scal[0], iZa = 1.f / scal[1];
    if (tid < 64) {
        float acc = 0.f;
        for (int m = 0; m < 64; m++) {
            float a = __expf(alog[m] - Ma) * iZa;
            acc += fabsf(tp[m * 64 + tid] - e[m * 64 + tid]) * a;
        }
        r1[tid] = fmaxf(acc, 0.f);
    }
    __syncthreads();
    if (tid < 128) {
        float acc = l3b[tid];
        for (int d = 0; d < 64; d++) acc = fmaf(r1[d], l3w[tid * 64 + d], acc);
        hid[tid] = fmaxf(acc, 0.f);
    }
    __syncthreads();
    if (tid < 2) {
        float acc = cb[tid];
        for (int j = 0; j < 128; j++) acc = fmaf(hid[j], cw[tid * 128 + j], acc);
        out[tid] = acc;
    }
}

// ---------------- weight packing ----------------
__global__ __launch_bounds__(256) void transpose_l1w_k(const float* __restrict__ w,
        float* __restrict__ wt) {
    int idx = blockIdx.x * 256 + threadIdx.x;
    if (idx >= KF * 64) return;
    int k = idx >> 6, j = idx & 63;
    wt[idx] = w[(size_t)j * KF + k];
}
__global__ __launch_bounds__(256) void pack_w1_k(const float* __restrict__ w,
        float* __restrict__ wp) {
    int idx = blockIdx.x * 256 + threadIdx.x;
    if (idx >= 400) return;
    int k = idx >> 4, co = idx & 15;
    wp[idx] = w[co * 25 + k];
}
__global__ __launch_bounds__(256) void pack_w2_k(const float* __restrict__ w,
        float* __restrict__ wp) {
    int idx = blockIdx.x * 256 + threadIdx.x;
    if (idx >= 12800) return;
    int co = idx & 31, rest = idx >> 5;
    wp[idx] = w[co * 400 + rest];
}
__global__ __launch_bounds__(256) void pack_w3_k(const float* __restrict__ w,
        float* __restrict__ wp) {
    int idx = blockIdx.x * 256 + threadIdx.x;
    if (idx >= 51200) return;
    int co = idx & 63, rest = idx >> 6;
    wp[idx] = w[co * 800 + rest];
}
__global__ __launch_bounds__(256) void pack_wih_k(const float* __restrict__ wih,
        const float* __restrict__ bih, const float* __restrict__ l1b,
        float* __restrict__ wiht, float* __restrict__ bc) {
    int idx = blockIdx.x * 256 + threadIdx.x;
    if (idx < 12288) {
        int g = idx % 192, k = idx / 192;
        wiht[idx] = wih[g * 64 + k];
    }
    if (idx < 192) {
        float acc = bih[idx];
#pragma unroll
        for (int k = 0; k < 64; k++) acc = fmaf(wih[idx * 64 + k], l1b[k], acc);
        bc[idx] = acc;
    }
}

// ---------------- host ----------------
extern "C" void kernel_launch(void* const* d_in, const int* in_sizes, int n_in,
                              void* d_out, int out_size, void* d_ws, size_t ws_size,
                              hipStream_t stream) {
    const float* ev    = (const float*)d_in[0];
    const float* tmpl  = (const float*)d_in[1];
    const float* w1    = (const float*)d_in[2];
    const float* b1    = (const float*)d_in[3];
    const float* w2    = (const float*)d_in[4];
    const float* b2    = (const float*)d_in[5];
    const float* w3    = (const float*)d_in[6];
    const float* b3    = (const float*)d_in[7];
    const float* l1w   = (const float*)d_in[8];
    const float* l1b   = (const float*)d_in[9];
    const float* wih   = (const float*)d_in[10];
    const float* whh   = (const float*)d_in[11];
    const float* bih   = (const float*)d_in[12];
    const float* bhh   = (const float*)d_in[13];
    const float* aw    = (const float*)d_in[14];
    const float* ab    = (const float*)d_in[15];
    const float* l3w   = (const float*)d_in[16];
    const float* l3b   = (const float*)d_in[17];
    const float* cw    = (const float*)d_in[18];
    const float* cb    = (const float*)d_in[19];
    float* out = (float*)d_out;
    (void)in_sizes; (void)n_in; (void)out_size;

    char* ws = (char*)d_ws;
    size_t off = 0;
    auto alloc = [&](size_t bytes) -> char* {
        char* p = ws + off;
        off += (bytes + 255) & ~(size_t)255;
        return p;
    };
    size_t szA = (size_t)C3 * H3 * W3 * 2;                 // fp16 conv3 out
    size_t szA1 = (size_t)C1 * H1 * W1 * 4;                // fp32 conv1 out
    if (szA1 > szA) szA = szA1;
    char*  A    = alloc(szA);
    float* B    = (float*)alloc((size_t)C2 * H2 * W2 * 4); // conv2 out / pooled
    float* Wt   = (float*)alloc((size_t)KF * 64 * 4);
    float* w1p  = (float*)alloc(400 * 4);
    float* w2p  = (float*)alloc(12800 * 4);
    float* w3p  = (float*)alloc(51200 * 4);
    float* wiht = (float*)alloc(12288 * 4);
    float* bc   = (float*)alloc(256 * 4);
    float* L    = (float*)alloc((size_t)HP * 64 * 4);
    float* gi0  = (float*)alloc((size_t)HP * 192 * 4);
    float* gi1  = (float*)alloc((size_t)HP * 192 * 4);
    float* ebuf = (float*)alloc((size_t)HP * 64 * 4);
    float* tbuf = (float*)alloc((size_t)HP * 64 * 4);
    float* pM   = (float*)alloc((size_t)8 * HP * 4);
    float* pZ   = (float*)alloc((size_t)8 * HP * 4);
    float* Mn   = (float*)alloc(HP * 4);
    float* Zn   = (float*)alloc(HP * 4);
    float* Wm   = (float*)alloc((size_t)64 * HP * 4);
    float* alog = (float*)alloc(HP * 4);
    float* tpm  = (float*)alloc(64 * 64 * 4);
    float* scal = (float*)alloc(256);
    if (off > ws_size) return;   // workspace too small: bail loudly (validation fails)

    transpose_l1w_k<<<dim3((KF * 64 + 255) / 256), dim3(256), 0, stream>>>(l1w, Wt);
    pack_w1_k<<<dim3(2), dim3(256), 0, stream>>>(w1, w1p);
    pack_w2_k<<<dim3(50), dim3(256), 0, stream>>>(w2, w2p);
    pack_w3_k<<<dim3(200), dim3(256), 0, stream>>>(w3, w3p);
    pack_wih_k<<<dim3(48), dim3(256), 0, stream>>>(wih, bih, l1b, wiht, bc);

    for (int bsel = 0; bsel < 2; bsel++) {
        const float* xin = bsel ? tmpl : ev;
        float* gib = bsel ? gi1 : gi0;
        conv1_k<<<dim3((H1 * W1 + 255) / 256), dim3(256), 0, stream>>>(xin, w1p, b1, (float*)A);
        conv2_k<<<dim3((H2 * W2 + 255) / 256), dim3(256), 0, stream>>>((const float*)A, w2p, b2, B);
        conv3_k<<<dim3((H3 * W3 + 255) / 256), dim3(256), 0, stream>>>(B, w3p, b3, (__half*)A);
        pool_k<<<dim3((C3 * HP * WPW + 255) / 256), dim3(256), 0, stream>>>((const __half*)A, B);
        hipMemsetAsync(L, 0, (size_t)HP * 64 * 4, stream);
        lin1_k<<<dim3(64, 4), dim3(256), 0, stream>>>(B, Wt, L);
        gi_k<<<dim3(HP), dim3(192), 0, stream>>>(L, wiht, bc, gib);
    }
    gru_k<<<dim3(2), dim3(192), 0, stream>>>(gi0, gi1, whh, bhh, ebuf, tbuf);
    astat_k<<<dim3(64, 8), dim3(256), 0, stream>>>(ebuf, tbuf, pM, pZ);
    attnlog_k<<<dim3(16), dim3(256), 0, stream>>>(ebuf, aw, ab, alog);
    reduce_k<<<dim3(17), dim3(256), 0, stream>>>(pM, pZ, Mn, Zn, alog, scal);
    wmat_k<<<dim3(16), dim3(256), 0, stream>>>(ebuf, tbuf, Mn, Zn, Wm);
    hipMemsetAsync(tpm, 0, 64 * 64 * 4, stream);
    tprim_k<<<dim3(64), dim3(256), 0, stream>>>(Wm, tbuf, tpm);
    final_k<<<dim3(1), dim3(256), 0, stream>>>(tpm, ebuf, alog, scal, l3w, l3b, cw, cb, out);
}